// Round 1
// baseline (256.928 us; speedup 1.0000x reference)
//
#include <hip/hip_runtime.h>
#include <math.h>

// Problem constants (from reference)
#define BB 16
#define VV 6890
#define NFF 13776
#define HH 512
#define WW 512
// SIGMA = 1e-4 -> 1/SIGMA = 1e4

typedef float nf4 __attribute__((ext_vector_type(4)));  // native vec4 for nontemporal ld/st
typedef int   ni4 __attribute__((ext_vector_type(4)));

// ---------------------------------------------------------------------------
// Stage 1: per-(batch,face) face normal, scattered atomically into per-(b,v)
// accumulators. Replaces the old fn-store + CSR build (count/scan/fill) + vn
// gather: 5 dispatches -> 1. vn region is 1.76 MB (L2-resident), ~2M float
// atomics total, contention ~6 per address.
// Grid is exact: BB*NFF = 220416 = 861 * 256 -> no bounds check.
// ---------------------------------------------------------------------------
__global__ __launch_bounds__(256) void k_fnacc(const float* __restrict__ verts,
                                               const int* __restrict__ faces,
                                               float* __restrict__ vn) {
    int i = blockIdx.x * 256 + threadIdx.x;
    int b = i / NFF;
    int f = i - b * NFF;
    int i0 = faces[3 * f + 0];
    int i1 = faces[3 * f + 1];
    int i2 = faces[3 * f + 2];
    const float* vb = verts + (size_t)b * (VV * 3);
    float ax = vb[3 * i0 + 0], ay = vb[3 * i0 + 1], az = vb[3 * i0 + 2];
    float bx = vb[3 * i1 + 0], by = vb[3 * i1 + 1], bz = vb[3 * i1 + 2];
    float cx = vb[3 * i2 + 0], cy = vb[3 * i2 + 1], cz = vb[3 * i2 + 2];
    float e1x = bx - ax, e1y = by - ay, e1z = bz - az;
    float e2x = cx - ax, e2y = cy - ay, e2z = cz - az;
    float nx = e1y * e2z - e1z * e2y;
    float ny = e1z * e2x - e1x * e2z;
    float nz = e1x * e2y - e1y * e2x;
    float* vbase = vn + (size_t)b * (VV * 4);  // float4-strided for vectorized gather later
    atomicAdd(vbase + 4 * i0 + 0, nx);
    atomicAdd(vbase + 4 * i0 + 1, ny);
    atomicAdd(vbase + 4 * i0 + 2, nz);
    atomicAdd(vbase + 4 * i1 + 0, nx);
    atomicAdd(vbase + 4 * i1 + 1, ny);
    atomicAdd(vbase + 4 * i1 + 2, nz);
    atomicAdd(vbase + 4 * i2 + 0, nx);
    atomicAdd(vbase + 4 * i2 + 1, ny);
    atomicAdd(vbase + 4 * i2 + 2, nz);
}

// ---------------------------------------------------------------------------
// Stage 2: face_attr_sum[b,f] = sum of the 3 normalized vertex normals.
// Normalization folded in here (each vertex normalized ~6x redundantly —
// 3 sqrt+div per thread, far cheaper than an extra kernel + 1.8MB round trip).
// ---------------------------------------------------------------------------
__global__ __launch_bounds__(256) void k_face_sum(const float4* __restrict__ vn4,
                                                  const int* __restrict__ faces,
                                                  float4* __restrict__ fas4) {
    int i = blockIdx.x * 256 + threadIdx.x;
    int b = i / NFF;
    int f = i - b * NFF;
    int i0 = faces[3 * f + 0], i1 = faces[3 * f + 1], i2 = faces[3 * f + 2];
    const float4* vnb = vn4 + (size_t)b * VV;
    float4 a = vnb[i0], bb = vnb[i1], cc = vnb[i2];
    float ia = 1.0f / fmaxf(sqrtf(a.x * a.x + a.y * a.y + a.z * a.z), 1e-6f);
    float ib = 1.0f / fmaxf(sqrtf(bb.x * bb.x + bb.y * bb.y + bb.z * bb.z), 1e-6f);
    float ic = 1.0f / fmaxf(sqrtf(cc.x * cc.x + cc.y * cc.y + cc.z * cc.z), 1e-6f);
    float4 o;
    o.x = a.x * ia + bb.x * ib + cc.x * ic;
    o.y = a.y * ia + bb.y * ib + cc.y * ic;
    o.z = a.z * ia + bb.z * ib + cc.z * ic;
    o.w = 0.f;
    fas4[i] = o;  // regular store: we WANT this resident in L2 for k_pixel
}

// ---------------------------------------------------------------------------
// Stage 3: per-pixel gather + normalize + alpha. 4 pixels per thread,
// XCD-aware block swizzle so each XCD's fas4 working set (~3.5MB, 2 batches
// per XCD, one hot at a time) fits its private 4MB L2 instead of thrashing
// to Infinity Cache.
// ---------------------------------------------------------------------------
__device__ __forceinline__ nf4 pixel_one(int f, float d, float4 p) {
    float m = (f >= 0) ? 1.0f : 0.0f;
    float px = p.x * m, py = p.y * m, pz = p.z * m;
    float prob = m / (1.0f + __expf(d * 1.0e4f));  // sigmoid(-d/SIGMA) * mask
    float n2 = px * px + py * py + pz * pz;
    float inv = 1.0f / fmaxf(sqrtf(n2), 1e-12f);
    float hitadd = (n2 > 0.f) ? 0.f : 1.0f;
    nf4 o;
    o.x = px * inv + hitadd;
    o.y = py * inv + hitadd;
    o.z = pz * inv + hitadd;
    o.w = 1.0f - prob;
    return o;
}

#define NPIXBLK 4096  // BB*HH*WW / 4 / 256 (exact)

__global__ __launch_bounds__(256) void k_pixel(const int* __restrict__ p2f,
                                               const float* __restrict__ dists,
                                               const float4* __restrict__ fas4,
                                               nf4* __restrict__ out) {
    int blk = blockIdx.x;
    // XCD swizzle: hw block i -> XCD i%8 (round-robin). Give XCD x the
    // contiguous logical range [x*512, (x+1)*512) = batches [2x, 2x+2).
    int lb = (blk & 7) * (NPIXBLK / 8) + (blk >> 3);
    int i = (lb * 256 + threadIdx.x) * 4;
    int b = i >> 18;  // H*W = 2^18; a 1024-pixel block never crosses a batch

    // Streamed inputs: nontemporal so they don't evict the fas4 slab from L2.
    ni4 ff = __builtin_nontemporal_load((const ni4*)(p2f + i));
    nf4 dd = __builtin_nontemporal_load((const nf4*)(dists + i));

    const float4* fasb = fas4 + (size_t)b * NFF;
    // Unconditional clamped gathers: all 4 issue back-to-back (max MLP),
    // invalid (-1) lanes read index 0 harmlessly and get masked in pixel_one.
    int c0 = min(max(ff[0], 0), NFF - 1);
    int c1 = min(max(ff[1], 0), NFF - 1);
    int c2 = min(max(ff[2], 0), NFF - 1);
    int c3 = min(max(ff[3], 0), NFF - 1);
    float4 p0 = fasb[c0];
    float4 p1 = fasb[c1];
    float4 p2 = fasb[c2];
    float4 p3 = fasb[c3];

    nf4 o0 = pixel_one(ff[0], dd[0], p0);
    nf4 o1 = pixel_one(ff[1], dd[1], p1);
    nf4 o2 = pixel_one(ff[2], dd[2], p2);
    nf4 o3 = pixel_one(ff[3], dd[3], p3);
    __builtin_nontemporal_store(o0, out + i + 0);
    __builtin_nontemporal_store(o1, out + i + 1);
    __builtin_nontemporal_store(o2, out + i + 2);
    __builtin_nontemporal_store(o3, out + i + 3);
}

// ---------------------------------------------------------------------------
extern "C" void kernel_launch(void* const* d_in, const int* in_sizes, int n_in,
                              void* d_out, int out_size, void* d_ws, size_t ws_size,
                              hipStream_t stream) {
    const float* verts = (const float*)d_in[0];
    // d_in[1] = zbuf: dead in the reference's returned value -> never read
    const float* dists = (const float*)d_in[2];
    const int* faces   = (const int*)d_in[3];
    const int* p2f     = (const int*)d_in[4];

    // Workspace layout (16B-aligned chunks)
    char* w = (char*)d_ws;
    float* vn    = (float*)w;   w += (size_t)BB * VV * 16;   // 1.76 MB accumulators
    float4* fas4 = (float4*)w;                               // 3.53 MB

    (void)hipMemsetAsync(vn, 0, (size_t)BB * VV * 16, stream);

    int nbf = BB * NFF;  // 220416 = 861 * 256 exactly
    k_fnacc<<<nbf / 256, 256, 0, stream>>>(verts, faces, vn);
    k_face_sum<<<nbf / 256, 256, 0, stream>>>((const float4*)vn, faces, fas4);
    k_pixel<<<NPIXBLK, 256, 0, stream>>>(p2f, dists, fas4, (nf4*)d_out);
}

// Round 2
// 253.207 us; speedup vs baseline: 1.0147x; 1.0147x over previous
//
#include <hip/hip_runtime.h>
#include <math.h>

// Problem constants (from reference)
#define BB 16
#define VV 6890
#define NFF 13776
#define HH 512
#define WW 512
// SIGMA = 1e-4 -> 1/SIGMA = 1e4

typedef float nf4 __attribute__((ext_vector_type(4)));
typedef int   ni4 __attribute__((ext_vector_type(4)));

#define NFLAT (3 * NFF)                     // 41328 flat face-vertex slots
#define CSR_T 256
#define CSR_CH ((VV + CSR_T - 1) / CSR_T)   // 27 vertices per thread in the scan

// ---------------------------------------------------------------------------
// Launch 1 (k_prep): blocks [0,861) compute per-(batch,face) normals into fn4
// (exact: 861*256 == BB*NFF, no tail). Block 861 builds the vertex->face CSR
// entirely in LDS (histogram + scan + fill) -- replaces memset + k_count +
// k_scan + k_fill from the old pipeline, zero global atomics. The CSR block
// runs concurrently with the fn blocks inside one dispatch.
// ---------------------------------------------------------------------------
__global__ __launch_bounds__(256) void k_prep(const float* __restrict__ verts,
                                              const int* __restrict__ faces,
                                              float4* __restrict__ fn4,
                                              int* __restrict__ offsets,
                                              int* __restrict__ adj) {
    __shared__ int cnt[VV];      // 27.56 KB: histogram, then exclusive offsets, then cursor
    __shared__ int part[CSR_T];

    if (blockIdx.x < 861) {
        int i = blockIdx.x * 256 + threadIdx.x;   // < 220416 exactly
        int b = i / NFF;
        int f = i - b * NFF;
        int i0 = faces[3 * f + 0];
        int i1 = faces[3 * f + 1];
        int i2 = faces[3 * f + 2];
        const float* vb = verts + (size_t)b * (VV * 3);
        float ax = vb[3 * i0 + 0], ay = vb[3 * i0 + 1], az = vb[3 * i0 + 2];
        float bx = vb[3 * i1 + 0], by = vb[3 * i1 + 1], bz = vb[3 * i1 + 2];
        float cx = vb[3 * i2 + 0], cy = vb[3 * i2 + 1], cz = vb[3 * i2 + 2];
        float e1x = bx - ax, e1y = by - ay, e1z = bz - az;
        float e2x = cx - ax, e2y = cy - ay, e2z = cz - az;
        float4 n;
        n.x = e1y * e2z - e1z * e2y;
        n.y = e1z * e2x - e1x * e2z;
        n.z = e1x * e2y - e1y * e2x;
        n.w = 0.f;
        fn4[i] = n;
        return;
    }

    // ---- CSR build block ----
    int t = threadIdx.x;
    for (int k = t; k < VV; k += CSR_T) cnt[k] = 0;
    __syncthreads();

    // Histogram via LDS atomics (coalesced reads of the flat faces array)
    for (int idx = t; idx < NFLAT; idx += CSR_T)
        atomicAdd(&cnt[faces[idx]], 1);
    __syncthreads();

    // Chunked exclusive scan: thread t owns vertices [t*27, t*27+27)
    int base = t * CSR_CH;
    int local = 0;
    for (int k = 0; k < CSR_CH; k++) {
        int idx = base + k;
        if (idx < VV) local += cnt[idx];
    }
    part[t] = local;
    __syncthreads();
    for (int off = 1; off < CSR_T; off <<= 1) {   // Hillis-Steele over 256 partials
        int v = part[t];
        int add = (t >= off) ? part[t - off] : 0;
        __syncthreads();
        part[t] = v + add;
        __syncthreads();
    }
    int running = (t == 0) ? 0 : part[t - 1];
    for (int k = 0; k < CSR_CH; k++) {
        int idx = base + k;
        if (idx < VV) {
            int c = cnt[idx];
            cnt[idx] = running;       // exclusive offset (becomes cursor below)
            offsets[idx] = running;   // publish to global for k_vn
            running += c;
        }
    }
    if (t == 0) offsets[VV] = NFLAT;
    __syncthreads();

    // Fill: cursor lives in LDS, no global atomics, no memset needed
    for (int idx = t; idx < NFLAT; idx += CSR_T) {
        int v = faces[idx];
        int pos = atomicAdd(&cnt[v], 1);
        adj[pos] = idx / 3;           // face id (compiler emits magic-mul div)
    }
}

// ---------------------------------------------------------------------------
// Launch 2: per-(batch,vertex) gather adjacent face normals, normalize
// ---------------------------------------------------------------------------
__global__ __launch_bounds__(256) void k_vn(const float4* __restrict__ fn4,
                                            const int* __restrict__ offsets,
                                            const int* __restrict__ adj,
                                            float4* __restrict__ vn4) {
    int i = blockIdx.x * 256 + threadIdx.x;
    if (i >= BB * VV) return;
    int b = i / VV;
    int v = i - b * VV;
    int s = offsets[v], e = offsets[v + 1];
    float x = 0.f, y = 0.f, z = 0.f;
    const float4* fnb = fn4 + (size_t)b * NFF;
    for (int j = s; j < e; j++) {
        float4 n = fnb[adj[j]];
        x += n.x; y += n.y; z += n.z;
    }
    float nrm = sqrtf(x * x + y * y + z * z);
    float inv = 1.0f / fmaxf(nrm, 1e-6f);
    float4 o; o.x = x * inv; o.y = y * inv; o.z = z * inv; o.w = 0.f;
    vn4[i] = o;
}

// ---------------------------------------------------------------------------
// Launch 3: face_attr_sum[b,f] = sum of the 3 normalized vertex normals
// ---------------------------------------------------------------------------
__global__ __launch_bounds__(256) void k_face_sum(const float4* __restrict__ vn4,
                                                  const int* __restrict__ faces,
                                                  float4* __restrict__ fas4) {
    int i = blockIdx.x * 256 + threadIdx.x;   // exact: 861*256 == BB*NFF
    int b = i / NFF;
    int f = i - b * NFF;
    int i0 = faces[3 * f + 0], i1 = faces[3 * f + 1], i2 = faces[3 * f + 2];
    const float4* vnb = vn4 + (size_t)b * VV;
    float4 a = vnb[i0], bb = vnb[i1], cc = vnb[i2];
    float4 o;
    o.x = a.x + bb.x + cc.x;
    o.y = a.y + bb.y + cc.y;
    o.z = a.z + bb.z + cc.z;
    o.w = 0.f;
    fas4[i] = o;
}

// ---------------------------------------------------------------------------
// Launch 4: per-pixel gather + normalize + alpha. 8 pixels/thread: all 8
// clamped gathers issue back-to-back (max memory-level parallelism) -- this
// kernel is gather-latency-bound, not BW-bound (round-0: 2.2 TB/s, ideal
// traffic). No XCD swizzle: per-batch fas4 slab is 220 KB, L2-fits regardless.
// ---------------------------------------------------------------------------
__device__ __forceinline__ nf4 pixel_one(int f, float d, float4 p) {
    float m = (f >= 0) ? 1.0f : 0.0f;
    float px = p.x * m, py = p.y * m, pz = p.z * m;
    float prob = m / (1.0f + __expf(d * 1.0e4f));  // sigmoid(-d/SIGMA) * mask
    float n2 = px * px + py * py + pz * pz;
    float inv = 1.0f / fmaxf(sqrtf(n2), 1e-12f);
    float hitadd = (n2 > 0.f) ? 0.f : 1.0f;
    nf4 o;
    o.x = px * inv + hitadd;
    o.y = py * inv + hitadd;
    o.z = pz * inv + hitadd;
    o.w = 1.0f - prob;
    return o;
}

__global__ __launch_bounds__(256) void k_pixel(const int* __restrict__ p2f,
                                               const float* __restrict__ dists,
                                               const float4* __restrict__ fas4,
                                               nf4* __restrict__ out) {
    int i = (blockIdx.x * 256 + threadIdx.x) * 8;
    int b = i >> 18;  // H*W = 2^18; an 8-pixel group never crosses a batch
    const float4* fasb = fas4 + (size_t)b * NFF;

    ni4 f0 = *(const ni4*)(p2f + i);
    ni4 f1 = *(const ni4*)(p2f + i + 4);
    nf4 d0 = *(const nf4*)(dists + i);
    nf4 d1 = *(const nf4*)(dists + i + 4);

    // Unconditional clamped gathers, fully unrolled (static indices only)
    float4 p0 = fasb[min(max(f0[0], 0), NFF - 1)];
    float4 p1 = fasb[min(max(f0[1], 0), NFF - 1)];
    float4 p2 = fasb[min(max(f0[2], 0), NFF - 1)];
    float4 p3 = fasb[min(max(f0[3], 0), NFF - 1)];
    float4 p4 = fasb[min(max(f1[0], 0), NFF - 1)];
    float4 p5 = fasb[min(max(f1[1], 0), NFF - 1)];
    float4 p6 = fasb[min(max(f1[2], 0), NFF - 1)];
    float4 p7 = fasb[min(max(f1[3], 0), NFF - 1)];

    nf4 o0 = pixel_one(f0[0], d0[0], p0);
    nf4 o1 = pixel_one(f0[1], d0[1], p1);
    nf4 o2 = pixel_one(f0[2], d0[2], p2);
    nf4 o3 = pixel_one(f0[3], d0[3], p3);
    nf4 o4 = pixel_one(f1[0], d1[0], p4);
    nf4 o5 = pixel_one(f1[1], d1[1], p5);
    nf4 o6 = pixel_one(f1[2], d1[2], p6);
    nf4 o7 = pixel_one(f1[3], d1[3], p7);

    __builtin_nontemporal_store(o0, out + i + 0);
    __builtin_nontemporal_store(o1, out + i + 1);
    __builtin_nontemporal_store(o2, out + i + 2);
    __builtin_nontemporal_store(o3, out + i + 3);
    __builtin_nontemporal_store(o4, out + i + 4);
    __builtin_nontemporal_store(o5, out + i + 5);
    __builtin_nontemporal_store(o6, out + i + 6);
    __builtin_nontemporal_store(o7, out + i + 7);
}

// ---------------------------------------------------------------------------
extern "C" void kernel_launch(void* const* d_in, const int* in_sizes, int n_in,
                              void* d_out, int out_size, void* d_ws, size_t ws_size,
                              hipStream_t stream) {
    const float* verts = (const float*)d_in[0];
    // d_in[1] = zbuf: dead in the reference's returned value -> never read
    const float* dists = (const float*)d_in[2];
    const int* faces   = (const int*)d_in[3];
    const int* p2f     = (const int*)d_in[4];

    // Workspace layout (16B-aligned chunks)
    char* w = (char*)d_ws;
    float4* fn4  = (float4*)w;  w += (size_t)BB * NFF * 16;          // 3.53 MB
    float4* vn4  = (float4*)w;  w += (size_t)BB * VV * 16;           // 1.76 MB
    float4* fas4 = (float4*)w;  w += (size_t)BB * NFF * 16;          // 3.53 MB
    int* offsets = (int*)w;     w += ((VV + 1) * 4 + 12) / 16 * 16;
    int* adj     = (int*)w;

    int nbv = BB * VV;   // 110240

    k_prep<<<862, 256, 0, stream>>>(verts, faces, fn4, offsets, adj);
    k_vn<<<(nbv + 255) / 256, 256, 0, stream>>>(fn4, offsets, adj, vn4);
    k_face_sum<<<861, 256, 0, stream>>>(vn4, faces, fas4);
    k_pixel<<<BB * HH * WW / 8 / 256, 256, 0, stream>>>(p2f, dists, fas4, (nf4*)d_out);
}